// Round 5
// baseline (513.364 us; speedup 1.0000x reference)
//
#include <hip/hip_runtime.h>
#include <hip/hip_fp16.h>
#include <cstdint>

#define D 128
#define BLK 256

constexpr float MINN    = 1e-15f;
constexpr float ATCLIP  = 1.0f - 1e-7f;
constexpr float BALLEPS = 4e-3f;

typedef _Float16 f16x8 __attribute__((ext_vector_type(8)));
typedef float    f32x4 __attribute__((ext_vector_type(4)));

union H4 { _Float16 h[4]; uint2 u2; };
union H8 { _Float16 h[8]; uint4 u4; };

typedef __attribute__((address_space(1))) const void gas_v;
typedef __attribute__((address_space(3))) void las_v;

__device__ __forceinline__ float red64(float v) {
    v += __shfl_xor(v, 1, 64);
    v += __shfl_xor(v, 2, 64);
    v += __shfl_xor(v, 4, 64);
    v += __shfl_xor(v, 8, 64);
    v += __shfl_xor(v, 16, 64);
    v += __shfl_xor(v, 32, 64);
    return v;
}

__device__ __forceinline__ int red64i(int v) {
    v += __shfl_xor(v, 1, 64);
    v += __shfl_xor(v, 2, 64);
    v += __shfl_xor(v, 4, 64);
    v += __shfl_xor(v, 8, 64);
    v += __shfl_xor(v, 16, 64);
    v += __shfl_xor(v, 32, 64);
    return v;
}

__device__ __forceinline__ float red16(float v) {
    v += __shfl_xor(v, 1, 64);
    v += __shfl_xor(v, 2, 64);
    v += __shfl_xor(v, 4, 64);
    v += __shfl_xor(v, 8, 64);
    return v;
}

// fast transcendentals (args here are small: |x| < ~16)
__device__ __forceinline__ float tanh_fast(float x) {   // x >= 0
    float e = __expf(2.f * fminf(x, 15.f));
    return __fdividef(e - 1.f, e + 1.f);
}
__device__ __forceinline__ float artanh_fast(float x) { // x in [0, 1)
    x = fminf(x, ATCLIP);
    return 0.5f * __logf(__fdividef(1.f + x, 1.f - x));
}

// ---------------------------------------------------------------------------
// Kernel 0: blocks 0..7  : W fp32 -> fp16, fragment-order layout.
//           blocks 8..   : zero cnt[] + lookback[] + sync counters.
// ---------------------------------------------------------------------------
__global__ __launch_bounds__(256) void k_prep(const float* __restrict__ W,
                                              _Float16* __restrict__ Wh,
                                              int* __restrict__ zero, int zeroInts)
{
    const int t = threadIdx.x;
    const int bid = blockIdx.x;
    if (bid < 8) {
        int i = bid * 256 + t;                // 0..2047
        int f = i >> 7;
        int r = i & 127;
        const float4* src = (const float4*)(W + r * 128 + f * 8);
        float4 v0 = src[0], v1 = src[1];
        H8 u;
        u.h[0] = (_Float16)v0.x; u.h[1] = (_Float16)v0.y;
        u.h[2] = (_Float16)v0.z; u.h[3] = (_Float16)v0.w;
        u.h[4] = (_Float16)v1.x; u.h[5] = (_Float16)v1.y;
        u.h[6] = (_Float16)v1.z; u.h[7] = (_Float16)v1.w;
        *(uint4*)(Wh + i * 8) = u.u4;
    } else {
        int i = (bid - 8) * 256 + t;
        int base = i * 4;
        if (base + 3 < zeroInts) {
            *(int4*)(zero + base) = make_int4(0, 0, 0, 0);
        } else if (base < zeroInts) {
            for (int k = base; k < zeroInts; ++k) zero[k] = 0;
        }
    }
}

// ---------------------------------------------------------------------------
// Shared device pieces
// ---------------------------------------------------------------------------
// Decoupled-lookback scan of one 1024-node chunk. s = 257 ints of shared mem.
__device__ __forceinline__ void scan_chunk_dev(
    const int* __restrict__ cnt, int* __restrict__ ptr,
    unsigned long long* __restrict__ lb, int N, int cid, int* s)
{
    const int t    = threadIdx.x;
    const int lane = t & 63;
    const int w    = t >> 6;

    int base = cid * 1024 + t * 4;
    int v0 = 0, v1 = 0, v2 = 0, v3 = 0;
    if (base + 3 < N) {
        int4 q = *(const int4*)&cnt[base];
        v0 = q.x; v1 = q.y; v2 = q.z; v3 = q.w;
    } else {
        if (base + 0 < N) v0 = cnt[base + 0];
        if (base + 1 < N) v1 = cnt[base + 1];
        if (base + 2 < N) v2 = cnt[base + 2];
        if (base + 3 < N) v3 = cnt[base + 3];
    }
    int sum = v0 + v1 + v2 + v3;
    s[t] = sum;
    __syncthreads();
    for (int off = 1; off < 256; off <<= 1) {
        int xv = (t >= off) ? s[t - off] : 0;
        __syncthreads();
        s[t] += xv;
        __syncthreads();
    }
    int excl  = s[t] - sum;
    int total = s[255];

    if (t == 255) {
        unsigned long long pkt =
            ((unsigned long long)((cid == 0) ? 2u : 1u) << 32) | (unsigned)total;
        __hip_atomic_store(&lb[cid], pkt, __ATOMIC_RELEASE, __HIP_MEMORY_SCOPE_AGENT);
        if (cid == 0) s[256] = 0;
    }
    if (cid > 0 && w == 3) {
        int exclb = 0;
        int j = cid - 1;
        while (true) {
            int idx = j - lane;
            unsigned f = 0; int v = 0;
            if (idx >= 0) {
                unsigned long long p;
                do {
                    p = __hip_atomic_load(&lb[idx], __ATOMIC_ACQUIRE, __HIP_MEMORY_SCOPE_AGENT);
                    f = (unsigned)(p >> 32);
                } while (f == 0);
                v = (int)(unsigned)(p & 0xffffffffu);
            }
            unsigned long long m2 = __ballot(f == 2u);
            if (m2) {
                int Lstop = __ffsll((long long)m2) - 1;
                int contrib = (lane <= Lstop) ? v : 0;
                exclb += red64i(contrib);
                break;
            } else {
                exclb += red64i((idx >= 0) ? v : 0);
                j -= 64;
            }
        }
        if (lane == 0) {
            unsigned long long pkt2 =
                ((unsigned long long)2u << 32) | (unsigned)(exclb + total);
            __hip_atomic_store(&lb[cid], pkt2, __ATOMIC_RELEASE, __HIP_MEMORY_SCOPE_AGENT);
            s[256] = exclb;
        }
    }
    __syncthreads();

    int r = excl + s[256];
    if (base + 0 < N) ptr[base + 0] = r; r += v0;
    if (base + 1 < N) ptr[base + 1] = r; r += v1;
    if (base + 2 < N) ptr[base + 2] = r; r += v2;
    if (base + 3 < N) ptr[base + 3] = r;
}

// Aggregation + epilogue for one node n (16 lanes li=0..15 cooperate).
__device__ __forceinline__ void agg_one(
    const char* __restrict__ htb, const int* __restrict__ ptr,
    const int* __restrict__ cnt, const int2* __restrict__ sorted,
    float a, float* __restrict__ out, int n, int li, int rmode)
{
    H8 own; own.u4 = *(const uint4*)(htb + (size_t)n * 256 + li * 16);
    float acc[8];
#pragma unroll
    for (int k = 0; k < 8; ++k) acc[k] = (float)own.h[k];

    int basep = ptr[n];
    int cn    = cnt[n];
    int s0    = rmode ? basep : basep - cn;
    int e0    = s0 + cn;

    const int lioff = li * 16;
    int j = s0;
    for (; j + 4 <= e0; j += 4) {
        int2 d0 = sorted[j];
        int2 d1 = sorted[j + 1];
        int2 d2 = sorted[j + 2];
        int2 d3 = sorted[j + 3];
        H8 g0, g1, g2, g3;
        g0.u4 = *(const uint4*)(htb + (unsigned)d0.x + lioff);
        g1.u4 = *(const uint4*)(htb + (unsigned)d1.x + lioff);
        g2.u4 = *(const uint4*)(htb + (unsigned)d2.x + lioff);
        g3.u4 = *(const uint4*)(htb + (unsigned)d3.x + lioff);
        float w0 = __int_as_float(d0.y);
        float w1 = __int_as_float(d1.y);
        float w2 = __int_as_float(d2.y);
        float w3 = __int_as_float(d3.y);
#pragma unroll
        for (int k = 0; k < 8; ++k) acc[k] = fmaf((float)g0.h[k], w0, acc[k]);
#pragma unroll
        for (int k = 0; k < 8; ++k) acc[k] = fmaf((float)g1.h[k], w1, acc[k]);
#pragma unroll
        for (int k = 0; k < 8; ++k) acc[k] = fmaf((float)g2.h[k], w2, acc[k]);
#pragma unroll
        for (int k = 0; k < 8; ++k) acc[k] = fmaf((float)g3.h[k], w3, acc[k]);
    }
    for (; j < e0; ++j) {
        int2 d = sorted[j];
        H8 g; g.u4 = *(const uint4*)(htb + (unsigned)d.x + lioff);
        float w = __int_as_float(d.y);
#pragma unroll
        for (int k = 0; k < 8; ++k) acc[k] = fmaf((float)g.h[k], w, acc[k]);
    }

    float pv = 0.f;
#pragma unroll
    for (int k = 0; k < 8; ++k) {
        float v = acc[k];
        v = (v >= 0.f) ? v : a * v;
        acc[k] = v;
        pv = fmaf(v, v, pv);
    }
    float m2 = red16(pv);
    float rc = fmaxf(sqrtf(m2), MINN);
    float te = tanh_fast(rc);
    const float maxn = 1.0f - BALLEPS;
    float fsc = __fdividef(fminf(fmaxf(te, MINN), maxn), rc);

    float4 o0 = make_float4(fsc * acc[0], fsc * acc[1], fsc * acc[2], fsc * acc[3]);
    float4 o1 = make_float4(fsc * acc[4], fsc * acc[5], fsc * acc[6], fsc * acc[7]);
    float4* orow = (float4*)(out + (size_t)n * D);
    orow[li * 2 + 0] = o0;
    orow[li * 2 + 1] = o1;
}

// ---------------------------------------------------------------------------
// FUSED kernel: node chain (blocks 0..NB_NODE-1) and edge chain (the rest)
// run CONCURRENTLY; one grid-wide arrive barrier; then all blocks aggregate.
// Co-residency of all G blocks is guaranteed by the host (occupancy query +
// __launch_bounds__), same assumption class as the decoupled-lookback scan.
// sync[0]=hist_done, sync[1]=scan_done, sync[2]=grid arrive (zeroed by prep).
// ---------------------------------------------------------------------------
__global__ __launch_bounds__(256, 4) void k_fused(
    const float* __restrict__ x, const _Float16* __restrict__ Wh,
    const float* __restrict__ b, uint2* __restrict__ ht,
    const int* __restrict__ ei, const float* __restrict__ ew,
    int* __restrict__ cnt, int* __restrict__ rank, int* __restrict__ ptr,
    unsigned long long* __restrict__ lb, int* __restrict__ sync,
    int2* __restrict__ sorted, const float* __restrict__ a_in,
    float* __restrict__ out, int N, int E, int G,
    int NB_NODE, int NB_EDGE, int nc, int njobs)
{
    __shared__ __align__(16) char smem[32768];
    const int t    = threadIdx.x;
    const int bid  = blockIdx.x;
    const int lane = t & 63;
    const int w    = t >> 6;

    if (bid < NB_NODE) {
        // ================= NODE ROLE =================
        float* xs = (float*)smem;

        // bias scale (b load fully retired here; pinned before any job vmem)
        float2 b2 = ((const float2*)b)[lane];
        float pb  = fmaf(b2.x, b2.x, b2.y * b2.y);
        float bn2 = red64(pb);
        float bnc    = fmaxf(sqrtf(bn2), MINN);
        float bscale = __fdividef(tanh_fast(bnc), bnc);
        const float y2 = bscale * bscale * bn2;
        __builtin_amdgcn_sched_barrier(0);

        const int c = lane & 15;
        const int g = lane >> 4;
        const int bnode = w * 16 + c;
        const int sw    = bnode & 7;
        const float* xrow = &xs[bnode * 128];
        const float4* b4  = (const float4*)b;
        uint2* lout = (uint2*)((char*)xs + (size_t)w * 8192);

        auto do_tile = [&]() {
            f32x4 Cf[8];
#pragma unroll
            for (int mt = 0; mt < 8; ++mt) Cf[mt] = (f32x4){0.f, 0.f, 0.f, 0.f};
            float px = 0.f;
#pragma unroll
            for (int s = 0; s < 4; ++s) {
                int q0 = s * 8 + g * 2;
                f32x4 lo = *(const f32x4*)&xrow[(q0 ^ sw) * 4];
                f32x4 hi = *(const f32x4*)&xrow[((q0 + 1) ^ sw) * 4];
                px = fmaf(lo[0], lo[0], px); px = fmaf(lo[1], lo[1], px);
                px = fmaf(lo[2], lo[2], px); px = fmaf(lo[3], lo[3], px);
                px = fmaf(hi[0], hi[0], px); px = fmaf(hi[1], hi[1], px);
                px = fmaf(hi[2], hi[2], px); px = fmaf(hi[3], hi[3], px);
                f16x8 Bf;
                Bf[0] = (_Float16)lo[0]; Bf[1] = (_Float16)lo[1];
                Bf[2] = (_Float16)lo[2]; Bf[3] = (_Float16)lo[3];
                Bf[4] = (_Float16)hi[0]; Bf[5] = (_Float16)hi[1];
                Bf[6] = (_Float16)hi[2]; Bf[7] = (_Float16)hi[3];
                const _Float16* wp = Wh + ((s * 4 + g) << 10) + (c << 3);
#pragma unroll
                for (int mt = 0; mt < 8; ++mt) {
                    f16x8 Af = *(const f16x8*)&wp[mt << 7];
                    Cf[mt] = __builtin_amdgcn_mfma_f32_16x16x32_f16(Af, Bf, Cf[mt], 0, 0, 0);
                }
            }
            float pm = 0.f, pdb = 0.f;
#pragma unroll
            for (int mt = 0; mt < 8; ++mt) {
                float4 bv = b4[mt * 4 + g];
                pm  = fmaf(Cf[mt][0], Cf[mt][0], pm);
                pm  = fmaf(Cf[mt][1], Cf[mt][1], pm);
                pm  = fmaf(Cf[mt][2], Cf[mt][2], pm);
                pm  = fmaf(Cf[mt][3], Cf[mt][3], pm);
                pdb = fmaf(Cf[mt][0], bv.x, pdb);
                pdb = fmaf(Cf[mt][1], bv.y, pdb);
                pdb = fmaf(Cf[mt][2], bv.z, pdb);
                pdb = fmaf(Cf[mt][3], bv.w, pdb);
            }
            float xn2 = px;
            xn2 += __shfl_xor(xn2, 16); xn2 += __shfl_xor(xn2, 32);
            pm  += __shfl_xor(pm, 16);  pm  += __shfl_xor(pm, 32);
            pdb += __shfl_xor(pdb, 16); pdb += __shfl_xor(pdb, 32);
            float pd = bscale * pdb;

            float xn      = fmaxf(sqrtf(xn2), MINN);
            float mxn_raw = sqrtf(pm);
            float mxn     = fmaxf(mxn_raw, MINN);
            float alpha   = __fdividef(tanh_fast(__fdividef(mxn, xn) * artanh_fast(xn)), mxn);
            if (mxn_raw <= 1e-10f) alpha = 0.f;

            float x2  = alpha * alpha * pm;
            float xy  = alpha * pd;
            float den = fmaxf(fmaf(x2, y2, 1.f + 2.f * xy), MINN);
            float ca  = __fdividef((1.f + 2.f * xy + y2) * alpha, den);
            float cb  = __fdividef(1.f - x2, den);

            float hn2 = ca * ca * pm + 2.f * ca * cb * pd + cb * cb * y2;
            float hn  = fmaxf(sqrtf(hn2), MINN);
            float lsc = __fdividef(artanh_fast(hn), hn);
            float s1  = lsc * ca;
            float s2b = lsc * cb * bscale;

#pragma unroll
            for (int mt = 0; mt < 8; ++mt) {
                float4 bv = b4[mt * 4 + g];
                H4 u;
                u.h[0] = (_Float16)fmaf(s1, Cf[mt][0], s2b * bv.x);
                u.h[1] = (_Float16)fmaf(s1, Cf[mt][1], s2b * bv.y);
                u.h[2] = (_Float16)fmaf(s1, Cf[mt][2], s2b * bv.z);
                u.h[3] = (_Float16)fmaf(s1, Cf[mt][3], s2b * bv.w);
                lout[c * 33 + mt * 4 + g] = u.u2;
            }
        };

        auto copyout = [&](int tb) {
#pragma unroll
            for (int it = 0; it < 8; ++it) {
                int lin  = it * BLK + t;
                int node = lin >> 5;
                int col  = lin & 31;
                int gn   = tb + node;
                if (gn < N) {
                    const uint2* lsrc = (const uint2*)((const char*)xs + (size_t)(node >> 4) * 8192);
                    ht[(size_t)gn * 32 + col] = lsrc[(node & 15) * 33 + col];
                }
            }
        };

        for (int job = bid; job < njobs; job += NB_NODE) {
            const int node0 = job * 128;
            __syncthreads();                 // xs free (prev copyout done)

            // vmem group A: async DMA tile0 -> own LDS region (oldest 8)
#pragma unroll
            for (int i = 0; i < 8; ++i) {
                int P      = (w * 8 + i) * 64 + lane;
                int node   = P >> 5;
                int q      = (P & 31) ^ (node & 7);
                int node_g = min(node0 + node, N - 1);
                const float* src = x + (size_t)node_g * 128 + q * 4;
                char* dst = (char*)xs + (size_t)(w * 8 + i) * 1024;
                __builtin_amdgcn_global_load_lds((gas_v*)src, (las_v*)dst, 16, 0, 0);
            }
            __builtin_amdgcn_sched_barrier(0);

            // vmem group B: register-prefetch tile1 (newest 8)
            f32x4 rv[8];
#pragma unroll
            for (int i = 0; i < 8; ++i) {
                int P      = (w * 8 + i) * 64 + lane;
                int node   = P >> 5;
                int q      = (P & 31) ^ (node & 7);
                int node_g = min(node0 + 64 + node, N - 1);
                rv[i] = *(const f32x4*)(x + (size_t)node_g * 128 + q * 4);
            }
            __builtin_amdgcn_sched_barrier(0);

            // tile0 ready for THIS wave (drains DMA; rv stays in flight)
            asm volatile("s_waitcnt vmcnt(8)" ::: "memory");
            __builtin_amdgcn_sched_barrier(0);

            do_tile();
            __syncthreads();
            copyout(node0);

            asm volatile("s_waitcnt lgkmcnt(0)" ::: "memory");
            __builtin_amdgcn_sched_barrier(0);
            __builtin_amdgcn_s_barrier();
            __builtin_amdgcn_sched_barrier(0);

#pragma unroll
            for (int i = 0; i < 8; ++i) {
                float* dst = (float*)((char*)xs + (size_t)(w * 8 + i) * 1024 + (size_t)lane * 16);
                *(f32x4*)dst = rv[i];
            }
            do_tile();
            __syncthreads();
            copyout(node0 + 64);
        }
    } else {
        // ================= EDGE ROLE =================
        const int ebid = bid - NB_NODE;
        const int per  = (E + NB_EDGE - 1) / NB_EDGE;
        const int es   = min(ebid * per, E);
        const int ee   = min(es + per, E);

        // ---- phase E1: histogram (+rank)
        for (int e = es + t; e < ee; e += BLK)
            rank[e] = atomicAdd(&cnt[ei[E + e]], 1);
        __syncthreads();
        if (t == 0) {
            __threadfence();
            atomicAdd(&sync[0], 1);
            while (__hip_atomic_load(&sync[0], __ATOMIC_ACQUIRE, __HIP_MEMORY_SCOPE_AGENT) < NB_EDGE)
                __builtin_amdgcn_s_sleep(4);
        }
        __syncthreads();

        // ---- phase E2: scan (first nc edge blocks)
        if (ebid < nc) {
            scan_chunk_dev(cnt, ptr, lb, N, ebid, (int*)smem);
            __syncthreads();
            if (t == 0) { __threadfence(); atomicAdd(&sync[1], 1); }
        }
        if (t == 0) {
            while (__hip_atomic_load(&sync[1], __ATOMIC_ACQUIRE, __HIP_MEMORY_SCOPE_AGENT) < nc)
                __builtin_amdgcn_s_sleep(4);
        }
        __syncthreads();

        // ---- phase E3: scatter (rank-based, no atomics; own rank slice)
        for (int e = es + t; e < ee; e += BLK) {
            int src = ei[e];
            int dst = ei[E + e];
            float wt = ew[e];
            sorted[ptr[dst] + rank[e]] = make_int2(src << 8, __float_as_int(wt));
        }
    }

    // ---- grid-wide arrive barrier (single-use counter; all G co-resident)
    __syncthreads();
    if (t == 0) {
        __threadfence();
        atomicAdd(&sync[2], 1);
        while (__hip_atomic_load(&sync[2], __ATOMIC_ACQUIRE, __HIP_MEMORY_SCOPE_AGENT) < G)
            __builtin_amdgcn_s_sleep(4);
    }
    __syncthreads();

    // ---- AGG phase: all blocks, grid-stride, 16 nodes per block-pass
    const float a = a_in[0];
    const int li  = t & 15;
    const int grp = t >> 4;
    for (int base = bid * 16; base < N; base += G * 16) {
        int n = base + grp;
        if (n < N) agg_one((const char*)ht, ptr, cnt, sorted, a, out, n, li, 1);
    }
}

// ---------------------------------------------------------------------------
// Fallback path kernels (r4 structure), used if capacity check fails.
// ---------------------------------------------------------------------------
__global__ __launch_bounds__(BLK) void k_node_mfma(
    const float* __restrict__ x, const _Float16* __restrict__ Wh,
    const float* __restrict__ b, uint2* __restrict__ ht, int N,
    const int* __restrict__ ei, int* __restrict__ cnt,
    int* __restrict__ rank, int E, int eslice, int use_rank)
{
    __shared__ float xs[64 * 128];

    const int t     = threadIdx.x;
    const int lane  = t & 63;
    const int w     = t >> 6;
    const int node0 = blockIdx.x * 128;
    const int e0    = blockIdx.x * eslice;

    int ed[4];
#pragma unroll
    for (int k = 0; k < 4; ++k) {
        int idx = min(e0 + k * BLK + t, E - 1);
        ed[k] = ei[E + idx];
    }
    __builtin_amdgcn_sched_barrier(0);

    float2 b2 = ((const float2*)b)[lane];
    __builtin_amdgcn_sched_barrier(0);

#pragma unroll
    for (int i = 0; i < 8; ++i) {
        int P      = (w * 8 + i) * 64 + lane;
        int node   = P >> 5;
        int q      = (P & 31) ^ (node & 7);
        int node_g = min(node0 + node, N - 1);
        const float* src = x + (size_t)node_g * 128 + q * 4;
        char* dst = (char*)xs + (size_t)(w * 8 + i) * 1024;
        __builtin_amdgcn_global_load_lds((gas_v*)src, (las_v*)dst, 16, 0, 0);
    }
    __builtin_amdgcn_sched_barrier(0);

    f32x4 rv[8];
#pragma unroll
    for (int i = 0; i < 8; ++i) {
        int P      = (w * 8 + i) * 64 + lane;
        int node   = P >> 5;
        int q      = (P & 31) ^ (node & 7);
        int node_g = min(node0 + 64 + node, N - 1);
        rv[i] = *(const f32x4*)(x + (size_t)node_g * 128 + q * 4);
    }
    __builtin_amdgcn_sched_barrier(0);

    float pb  = fmaf(b2.x, b2.x, b2.y * b2.y);
    float bn2 = red64(pb);
    float bnc    = fmaxf(sqrtf(bn2), MINN);
    float bscale = __fdividef(tanh_fast(bnc), bnc);
    const float y2 = bscale * bscale * bn2;

    const int c = lane & 15;
    const int g = lane >> 4;
    const int bnode = w * 16 + c;
    const int sw    = bnode & 7;
    const float* xrow = &xs[bnode * 128];
    const float4* b4  = (const float4*)b;
    uint2* lout = (uint2*)((char*)xs + (size_t)w * 8192);

    auto do_tile = [&]() {
        f32x4 Cf[8];
#pragma unroll
        for (int mt = 0; mt < 8; ++mt) Cf[mt] = (f32x4){0.f, 0.f, 0.f, 0.f};
        float px = 0.f;
#pragma unroll
        for (int s = 0; s < 4; ++s) {
            int q0 = s * 8 + g * 2;
            f32x4 lo = *(const f32x4*)&xrow[(q0 ^ sw) * 4];
            f32x4 hi = *(const f32x4*)&xrow[((q0 + 1) ^ sw) * 4];
            px = fmaf(lo[0], lo[0], px); px = fmaf(lo[1], lo[1], px);
            px = fmaf(lo[2], lo[2], px); px = fmaf(lo[3], lo[3], px);
            px = fmaf(hi[0], hi[0], px); px = fmaf(hi[1], hi[1], px);
            px = fmaf(hi[2], hi[2], px); px = fmaf(hi[3], hi[3], px);
            f16x8 Bf;
            Bf[0] = (_Float16)lo[0]; Bf[1] = (_Float16)lo[1];
            Bf[2] = (_Float16)lo[2]; Bf[3] = (_Float16)lo[3];
            Bf[4] = (_Float16)hi[0]; Bf[5] = (_Float16)hi[1];
            Bf[6] = (_Float16)hi[2]; Bf[7] = (_Float16)hi[3];
            const _Float16* wp = Wh + ((s * 4 + g) << 10) + (c << 3);
#pragma unroll
            for (int mt = 0; mt < 8; ++mt) {
                f16x8 Af = *(const f16x8*)&wp[mt << 7];
                Cf[mt] = __builtin_amdgcn_mfma_f32_16x16x32_f16(Af, Bf, Cf[mt], 0, 0, 0);
            }
        }
        float pm = 0.f, pdb = 0.f;
#pragma unroll
        for (int mt = 0; mt < 8; ++mt) {
            float4 bv = b4[mt * 4 + g];
            pm  = fmaf(Cf[mt][0], Cf[mt][0], pm);
            pm  = fmaf(Cf[mt][1], Cf[mt][1], pm);
            pm  = fmaf(Cf[mt][2], Cf[mt][2], pm);
            pm  = fmaf(Cf[mt][3], Cf[mt][3], pm);
            pdb = fmaf(Cf[mt][0], bv.x, pdb);
            pdb = fmaf(Cf[mt][1], bv.y, pdb);
            pdb = fmaf(Cf[mt][2], bv.z, pdb);
            pdb = fmaf(Cf[mt][3], bv.w, pdb);
        }
        float xn2 = px;
        xn2 += __shfl_xor(xn2, 16); xn2 += __shfl_xor(xn2, 32);
        pm  += __shfl_xor(pm, 16);  pm  += __shfl_xor(pm, 32);
        pdb += __shfl_xor(pdb, 16); pdb += __shfl_xor(pdb, 32);
        float pd = bscale * pdb;

        float xn      = fmaxf(sqrtf(xn2), MINN);
        float mxn_raw = sqrtf(pm);
        float mxn     = fmaxf(mxn_raw, MINN);
        float alpha   = __fdividef(tanh_fast(__fdividef(mxn, xn) * artanh_fast(xn)), mxn);
        if (mxn_raw <= 1e-10f) alpha = 0.f;

        float x2  = alpha * alpha * pm;
        float xy  = alpha * pd;
        float den = fmaxf(fmaf(x2, y2, 1.f + 2.f * xy), MINN);
        float ca  = __fdividef((1.f + 2.f * xy + y2) * alpha, den);
        float cb  = __fdividef(1.f - x2, den);

        float hn2 = ca * ca * pm + 2.f * ca * cb * pd + cb * cb * y2;
        float hn  = fmaxf(sqrtf(hn2), MINN);
        float lsc = __fdividef(artanh_fast(hn), hn);
        float s1  = lsc * ca;
        float s2b = lsc * cb * bscale;

#pragma unroll
        for (int mt = 0; mt < 8; ++mt) {
            float4 bv = b4[mt * 4 + g];
            H4 u;
            u.h[0] = (_Float16)fmaf(s1, Cf[mt][0], s2b * bv.x);
            u.h[1] = (_Float16)fmaf(s1, Cf[mt][1], s2b * bv.y);
            u.h[2] = (_Float16)fmaf(s1, Cf[mt][2], s2b * bv.z);
            u.h[3] = (_Float16)fmaf(s1, Cf[mt][3], s2b * bv.w);
            lout[c * 33 + mt * 4 + g] = u.u2;
        }
    };

    auto copyout = [&](int tb) {
#pragma unroll
        for (int it = 0; it < 8; ++it) {
            int lin  = it * BLK + t;
            int node = lin >> 5;
            int col  = lin & 31;
            int gn   = tb + node;
            if (gn < N) {
                const uint2* lsrc = (const uint2*)((const char*)xs + (size_t)(node >> 4) * 8192);
                ht[(size_t)gn * 32 + col] = lsrc[(node & 15) * 33 + col];
            }
        }
    };

    asm volatile("s_waitcnt vmcnt(8)" ::: "memory");
    __builtin_amdgcn_sched_barrier(0);

    do_tile();
    __syncthreads();
    copyout(node0);

    asm volatile("s_waitcnt lgkmcnt(0)" ::: "memory");
    __builtin_amdgcn_sched_barrier(0);
    __builtin_amdgcn_s_barrier();
    __builtin_amdgcn_sched_barrier(0);

#pragma unroll
    for (int i = 0; i < 8; ++i) {
        float* dst = (float*)((char*)xs + (size_t)(w * 8 + i) * 1024 + (size_t)lane * 16);
        *(f32x4*)dst = rv[i];
    }
    do_tile();
    __syncthreads();
    copyout(node0 + 64);

#pragma unroll
    for (int k = 0; k < 4; ++k) {
        int i = k * BLK + t;
        int e = e0 + i;
        if (i < eslice && e < E) {
            int r = atomicAdd(&cnt[ed[k]], 1);
            if (use_rank) rank[e] = r;
        }
    }
    for (int i = 4 * BLK + t; i < eslice; i += BLK) {
        int e = e0 + i;
        if (e < E) {
            int r = atomicAdd(&cnt[ei[E + e]], 1);
            if (use_rank) rank[e] = r;
        }
    }
}

__global__ __launch_bounds__(256) void k_scan(
    const int* __restrict__ cnt, int* __restrict__ ptr,
    unsigned long long* __restrict__ lb, int N)
{
    __shared__ int s[257];
    scan_chunk_dev(cnt, ptr, lb, N, blockIdx.x, s);
}

__global__ __launch_bounds__(256) void k_scatter_rank(
    const int* __restrict__ ei, const float* __restrict__ ew,
    const int* __restrict__ ptr, const int* __restrict__ rank,
    int2* __restrict__ sorted, int E)
{
    int e = blockIdx.x * 256 + threadIdx.x;
    if (e >= E) return;
    int src = ei[e];
    int dst = ei[E + e];
    float wt = ew[e];
    sorted[ptr[dst] + rank[e]] = make_int2(src << 8, __float_as_int(wt));
}

__global__ __launch_bounds__(256) void k_scatter_atomic(
    const int* __restrict__ ei, const float* __restrict__ ew,
    int* __restrict__ ptr, int2* __restrict__ sorted, int E)
{
    int e = blockIdx.x * 256 + threadIdx.x;
    if (e >= E) return;
    int src = ei[e];
    int dst = ei[E + e];
    float wt = ew[e];
    int pos = atomicAdd(&ptr[dst], 1);
    sorted[pos] = make_int2(src << 8, __float_as_int(wt));
}

__global__ __launch_bounds__(256) void k_agg_final(
    const char* __restrict__ htb, const int* __restrict__ ptr,
    const int* __restrict__ cnt, const int2* __restrict__ sorted,
    const float* __restrict__ a_in, float* __restrict__ out, int N, int rmode)
{
    const int t   = threadIdx.x;
    const int li  = t & 15;
    const int grp = t >> 4;
    const int n   = blockIdx.x * 16 + grp;
    if (n >= N) return;
    agg_one(htb, ptr, cnt, sorted, a_in[0], (float*)out, n, li, rmode);
}

// ---------------------------------------------------------------------------
extern "C" void kernel_launch(void* const* d_in, const int* in_sizes, int n_in,
                              void* d_out, int out_size, void* d_ws, size_t ws_size,
                              hipStream_t stream)
{
    const float* x  = (const float*)d_in[0];
    const int*   ei = (const int*)  d_in[1];
    const float* ew = (const float*)d_in[2];
    const float* W  = (const float*)d_in[3];
    const float* b  = (const float*)d_in[4];
    const float* a  = (const float*)d_in[5];
    float* out = (float*)d_out;

    const int N = in_sizes[0] / D;
    const int E = in_sizes[1] / 2;
    const int nc = (N + 1023) / 1024;
    const int njobs = (N + 127) / 128;

    // workspace carve-up
    char* ws = (char*)d_ws;
    size_t HT_B       = (size_t)N * D * 2;
    uint2*              ht  = (uint2*)ws;
    size_t off_cnt    = HT_B;
    int*                cnt = (int*)(ws + off_cnt);
    size_t off_lb     = (off_cnt + (size_t)N * 4 + 15) & ~(size_t)15;
    unsigned long long* lb  = (unsigned long long*)(ws + off_lb);
    size_t off_sync   = (off_lb + (size_t)nc * 8 + 15) & ~(size_t)15;
    int*                syncp = (int*)(ws + off_sync);
    size_t off_ptr    = (off_sync + 16 + 15) & ~(size_t)15;
    int*                ptr = (int*)(ws + off_ptr);
    size_t off_sorted = (off_ptr + (size_t)N * 4 + 15) & ~(size_t)15;
    int2*               sorted = (int2*)(ws + off_sorted);
    size_t off_wh     = off_sorted + (size_t)E * 8;
    _Float16*           Wh  = (_Float16*)(ws + off_wh);
    size_t off_rank   = off_wh + 32768;
    int*                rank = (int*)(ws + off_rank);
    int use_rank = (ws_size >= off_rank + (size_t)E * 4) ? 1 : 0;

    int zeroInts = (int)((off_ptr - off_cnt) / 4);   // cnt + lb + sync (+pad)
    int zb  = ((zeroInts + 3) / 4 + 255) / 256;

    // co-resident capacity for the fused kernel (static, queried once)
    static int s_cap = -1;
    if (s_cap < 0) {
        int dev = 0;
        hipGetDevice(&dev);
        hipDeviceProp_t prop;
        int cus = 256;
        if (hipGetDeviceProperties(&prop, dev) == hipSuccess) cus = prop.multiProcessorCount;
        int maxB = 0;
        if (hipOccupancyMaxActiveBlocksPerMultiprocessor(&maxB, k_fused, 256, 0) != hipSuccess)
            maxB = 0;
        s_cap = maxB * cus;
        if (s_cap < 0) s_cap = 0;
    }
    int G = s_cap > 1280 ? 1280 : s_cap;
    int NB_EDGE = G - njobs;
    if (NB_EDGE < nc)  NB_EDGE = nc;
    if (NB_EDGE > 512) NB_EDGE = 512;
    int NB_NODE = G - NB_EDGE;
    bool fused_ok = use_rank && (G >= nc + 64) && (NB_NODE >= 1);

    k_prep<<<8 + zb, 256, 0, stream>>>(W, Wh, cnt, zeroInts);

    if (fused_ok) {
        k_fused<<<G, 256, 0, stream>>>(x, Wh, b, ht, ei, ew, cnt, rank, ptr,
                                       lb, syncp, sorted, a, out,
                                       N, E, G, NB_NODE, NB_EDGE, nc, njobs);
    } else {
        int nb1 = njobs;
        int eslice = (E + nb1 - 1) / nb1;
        k_node_mfma<<<nb1, BLK, 0, stream>>>(x, Wh, b, ht, N, ei, cnt,
                                             use_rank ? rank : nullptr, E, eslice, use_rank);
        k_scan<<<nc, 256, 0, stream>>>(cnt, ptr, lb, N);
        if (use_rank)
            k_scatter_rank<<<(E + 255) / 256, 256, 0, stream>>>(ei, ew, ptr, rank, sorted, E);
        else
            k_scatter_atomic<<<(E + 255) / 256, 256, 0, stream>>>(ei, ew, ptr, sorted, E);
        k_agg_final<<<(N + 15) / 16, 256, 0, stream>>>((const char*)ht, ptr, cnt, sorted, a, out, N, use_rank);
    }
}

// Round 6
// 193.517 us; speedup vs baseline: 2.6528x; 2.6528x over previous
//
#include <hip/hip_runtime.h>
#include <hip/hip_fp16.h>
#include <cstdint>

#define D 128
#define BLK 256

constexpr float MINN    = 1e-15f;
constexpr float ATCLIP  = 1.0f - 1e-7f;
constexpr float BALLEPS = 4e-3f;

typedef _Float16 f16x8 __attribute__((ext_vector_type(8)));
typedef float    f32x4 __attribute__((ext_vector_type(4)));

union H4 { _Float16 h[4]; uint2 u2; };
union H8 { _Float16 h[8]; uint4 u4; };

typedef __attribute__((address_space(1))) const void gas_v;
typedef __attribute__((address_space(3))) void las_v;

__device__ __forceinline__ float red64(float v) {
    v += __shfl_xor(v, 1, 64);
    v += __shfl_xor(v, 2, 64);
    v += __shfl_xor(v, 4, 64);
    v += __shfl_xor(v, 8, 64);
    v += __shfl_xor(v, 16, 64);
    v += __shfl_xor(v, 32, 64);
    return v;
}

__device__ __forceinline__ int red64i(int v) {
    v += __shfl_xor(v, 1, 64);
    v += __shfl_xor(v, 2, 64);
    v += __shfl_xor(v, 4, 64);
    v += __shfl_xor(v, 8, 64);
    v += __shfl_xor(v, 16, 64);
    v += __shfl_xor(v, 32, 64);
    return v;
}

__device__ __forceinline__ float red16(float v) {
    v += __shfl_xor(v, 1, 64);
    v += __shfl_xor(v, 2, 64);
    v += __shfl_xor(v, 4, 64);
    v += __shfl_xor(v, 8, 64);
    return v;
}

// fast transcendentals (args here are small: |x| < ~16)
__device__ __forceinline__ float tanh_fast(float x) {   // x >= 0
    float e = __expf(2.f * fminf(x, 15.f));
    return __fdividef(e - 1.f, e + 1.f);
}
__device__ __forceinline__ float artanh_fast(float x) { // x in [0, 1)
    x = fminf(x, ATCLIP);
    return 0.5f * __logf(__fdividef(1.f + x, 1.f - x));
}

// ---------------------------------------------------------------------------
// Kernel 0: blocks 0..7  : W fp32 -> fp16, fragment-order layout.
//           blocks 8..   : zero cnt[] + lookback[] region.
// Wh[f*1024 + r*8 + j] = (fp16) W[r][f*8+j],  f = k-chunk 0..15, r = row 0..127.
// ---------------------------------------------------------------------------
__global__ __launch_bounds__(256) void k_prep(const float* __restrict__ W,
                                              _Float16* __restrict__ Wh,
                                              int* __restrict__ zero, int zeroInts)
{
    const int t = threadIdx.x;
    const int bid = blockIdx.x;
    if (bid < 8) {
        int i = bid * 256 + t;                // 0..2047
        int f = i >> 7;
        int r = i & 127;
        const float4* src = (const float4*)(W + r * 128 + f * 8);
        float4 v0 = src[0], v1 = src[1];
        H8 u;
        u.h[0] = (_Float16)v0.x; u.h[1] = (_Float16)v0.y;
        u.h[2] = (_Float16)v0.z; u.h[3] = (_Float16)v0.w;
        u.h[4] = (_Float16)v1.x; u.h[5] = (_Float16)v1.y;
        u.h[6] = (_Float16)v1.z; u.h[7] = (_Float16)v1.w;
        *(uint4*)(Wh + i * 8) = u.u4;
    } else {
        int i = (bid - 8) * 256 + t;          // int4 index
        int base = i * 4;
        if (base + 3 < zeroInts) {
            *(int4*)(zero + base) = make_int4(0, 0, 0, 0);
        } else if (base < zeroInts) {
            for (int k = base; k < zeroInts; ++k) zero[k] = 0;
        }
    }
}

// ---------------------------------------------------------------------------
// Kernel 1 (MFMA): h_t = logmap0( mobius_add( mobius_matvec(W,x), expmap0(b) ) )
// 64 nodes/block, 4 waves, 32 KB LDS (r1 structure == best measured), with
// ONE structural fix: the first __syncthreads() (whose only purpose was the
// DMA drain) is replaced by a per-wave s_waitcnt vmcnt(0). Everything before
// the transpose/copy-out sync is wave-private (DMA region, MFMA inputs,
// transpose region), so no cross-wave ordering is needed and waves no longer
// convoy on the block's slowest DMA.
// In-degree histogram (+rank) runs in the tail, operands loaded IN the tail
// (keeps VGPR at the r1 level; r4's whole-kernel preload cost occupancy).
// ---------------------------------------------------------------------------
__global__ __launch_bounds__(BLK) void k_node_mfma(
    const float* __restrict__ x, const _Float16* __restrict__ Wh,
    const float* __restrict__ b, uint2* __restrict__ ht, int N,
    const int* __restrict__ ei, int* __restrict__ cnt,
    int* __restrict__ rank, int E, int eslice, int use_rank)
{
    __shared__ float xs[64 * 128];      // 32768 B fp32, swizzled (overlaid later)

    const int t     = threadIdx.x;
    const int node0 = blockIdx.x * 64;
    const int lane  = t & 63;
    const int w     = t >> 6;

    // ---- vmem group 1 (oldest): bias
    float2 b2 = ((const float2*)b)[lane];     // 64 lanes x 2 = all 128 dims
    __builtin_amdgcn_sched_barrier(0);

    // ---- vmem group 2: async DMA x -> own wave's LDS region (8 x 1KB)
#pragma unroll
    for (int i = 0; i < 8; ++i) {
        int P      = (w * 8 + i) * 64 + lane;       // LDS chunk slot 0..2047
        int node   = P >> 5;
        int q      = (P & 31) ^ (node & 7);         // swizzle: slot p holds chunk p^(n&7)
        int node_g = min(node0 + node, N - 1);      // clamp OOB tail (stores guarded later)
        const float* src = x + (size_t)node_g * 128 + q * 4;
        char* dst = (char*)xs + (size_t)(w * 8 + i) * 1024;   // wave-uniform base
        __builtin_amdgcn_global_load_lds((gas_v*)src, (las_v*)dst, 16, 0, 0);
    }
    __builtin_amdgcn_sched_barrier(0);

    // ---- bscale for p = expmap0(b) = bscale*b (waits b only: vmcnt(8))
    float pb  = fmaf(b2.x, b2.x, b2.y * b2.y);
    float bn2 = red64(pb);
    float bnc    = fmaxf(sqrtf(bn2), MINN);
    float bscale = __fdividef(tanh_fast(bnc), bnc);
    const float y2 = bscale * bscale * bn2;   // ||p||^2

    // ---- per-wave DMA drain (NO barrier: region is wave-private)
    asm volatile("s_waitcnt vmcnt(0)" ::: "memory");
    __builtin_amdgcn_sched_barrier(0);

    // ---- MFMA: mx[128 out][16 nodes] per wave
    const int c = lane & 15;        // node within wave-tile / W row within m-tile
    const int g = lane >> 4;        // quad

    f32x4 Cf[8];
#pragma unroll
    for (int mt = 0; mt < 8; ++mt) Cf[mt] = (f32x4){0.f, 0.f, 0.f, 0.f};

    const int bnode = w * 16 + c;
    const int sw    = bnode & 7;
    const float* xrow = &xs[bnode * 128];
    float px = 0.f;                 // fp32 ||x||^2 partial (this lane's 32 dims)

#pragma unroll
    for (int s = 0; s < 4; ++s) {
        int q0 = s * 8 + g * 2;
        f32x4 lo = *(const f32x4*)&xrow[(q0 ^ sw) * 4];
        f32x4 hi = *(const f32x4*)&xrow[((q0 + 1) ^ sw) * 4];
        px = fmaf(lo[0], lo[0], px); px = fmaf(lo[1], lo[1], px);
        px = fmaf(lo[2], lo[2], px); px = fmaf(lo[3], lo[3], px);
        px = fmaf(hi[0], hi[0], px); px = fmaf(hi[1], hi[1], px);
        px = fmaf(hi[2], hi[2], px); px = fmaf(hi[3], hi[3], px);
        f16x8 Bf;
        Bf[0] = (_Float16)lo[0]; Bf[1] = (_Float16)lo[1];
        Bf[2] = (_Float16)lo[2]; Bf[3] = (_Float16)lo[3];
        Bf[4] = (_Float16)hi[0]; Bf[5] = (_Float16)hi[1];
        Bf[6] = (_Float16)hi[2]; Bf[7] = (_Float16)hi[3];
        const _Float16* wp = Wh + ((s * 4 + g) << 10) + (c << 3);
#pragma unroll
        for (int mt = 0; mt < 8; ++mt) {
            f16x8 Af = *(const f16x8*)&wp[mt << 7];
            Cf[mt] = __builtin_amdgcn_mfma_f32_16x16x32_f16(Af, Bf, Cf[mt], 0, 0, 0);
        }
    }
    // lane holds mx[mt*16 + g*4 + r][node0 + w*16 + c] in Cf[mt][r]

    // ---- per-node epilogue (4 lanes per node via quads)
    // p = bscale*b, so <mx,p> = bscale * <mx,b>: accumulate against b (L1-hot)
    const float4* b4 = (const float4*)b;
    float pm = 0.f, pdb = 0.f;
#pragma unroll
    for (int mt = 0; mt < 8; ++mt) {
        float4 bv = b4[mt * 4 + g];
        pm  = fmaf(Cf[mt][0], Cf[mt][0], pm);
        pm  = fmaf(Cf[mt][1], Cf[mt][1], pm);
        pm  = fmaf(Cf[mt][2], Cf[mt][2], pm);
        pm  = fmaf(Cf[mt][3], Cf[mt][3], pm);
        pdb = fmaf(Cf[mt][0], bv.x, pdb);
        pdb = fmaf(Cf[mt][1], bv.y, pdb);
        pdb = fmaf(Cf[mt][2], bv.z, pdb);
        pdb = fmaf(Cf[mt][3], bv.w, pdb);
    }
    float xn2 = px;
    xn2 += __shfl_xor(xn2, 16); xn2 += __shfl_xor(xn2, 32);   // ||x||^2 (exact fp32)
    pm  += __shfl_xor(pm, 16);  pm  += __shfl_xor(pm, 32);    // ||mx||^2
    pdb += __shfl_xor(pdb, 16); pdb += __shfl_xor(pdb, 32);   // <mx, b>
    float pd = bscale * pdb;                                  // <mx, p>

    float xn      = fmaxf(sqrtf(xn2), MINN);
    float mxn_raw = sqrtf(pm);
    float mxn     = fmaxf(mxn_raw, MINN);
    float alpha   = __fdividef(tanh_fast(__fdividef(mxn, xn) * artanh_fast(xn)), mxn);
    if (mxn_raw <= 1e-10f) alpha = 0.f;     // zero-row guard

    float x2  = alpha * alpha * pm;
    float xy  = alpha * pd;
    float den = fmaxf(fmaf(x2, y2, 1.f + 2.f * xy), MINN);
    float ca  = __fdividef((1.f + 2.f * xy + y2) * alpha, den);
    float cb  = __fdividef(1.f - x2, den);

    // ||h||^2 analytically: h = ca*mx + cb*p
    float hn2 = ca * ca * pm + 2.f * ca * cb * pd + cb * cb * y2;
    float hn  = fmaxf(sqrtf(hn2), MINN);
    float lsc = __fdividef(artanh_fast(hn), hn);
    float s1  = lsc * ca;
    float s2b = lsc * cb * bscale;          // scale applied directly to b

    // ---- pack to fp16 via LDS transpose into OWN wave region (in-wave LDS
    // ordering: reads above retire before these writes -> no barrier)
    uint2* lout = (uint2*)((char*)xs + (size_t)w * 8192);
#pragma unroll
    for (int mt = 0; mt < 8; ++mt) {
        float4 bv = b4[mt * 4 + g];
        H4 u;
        u.h[0] = (_Float16)fmaf(s1, Cf[mt][0], s2b * bv.x);
        u.h[1] = (_Float16)fmaf(s1, Cf[mt][1], s2b * bv.y);
        u.h[2] = (_Float16)fmaf(s1, Cf[mt][2], s2b * bv.z);
        u.h[3] = (_Float16)fmaf(s1, Cf[mt][3], s2b * bv.w);
        lout[c * 33 + mt * 4 + g] = u.u2;   // col = mt*4+g holds dims 4col..4col+3
    }
    __syncthreads();    // the ONE barrier: all waves' transposes visible

    // ---- coalesced copy-out
    for (int it = 0; it < 8; ++it) {
        int lin  = it * BLK + t;        // 2048 uint2
        int node = lin >> 5;
        int col  = lin & 31;
        int gn   = node0 + node;
        if (gn < N) {
            const uint2* lsrc = (const uint2*)((const char*)xs + (size_t)(node >> 4) * 8192);
            ht[(size_t)gn * 32 + col] = lsrc[(node & 15) * 33 + col];
        }
    }

    // ---- in-degree histogram TAIL: loads issued here (short register
    // lifetime), contended atomics overlap other blocks' compute/retirement.
    __builtin_amdgcn_sched_barrier(0);
    {
        int e0 = blockIdx.x * eslice;
        for (int i = t; i < eslice; i += BLK) {
            int e = e0 + i;
            if (e < E) {
                int r = atomicAdd(&cnt[ei[E + e]], 1);
                if (use_rank) rank[e] = r;
            }
        }
    }
}

// ---------------------------------------------------------------------------
// Single-pass scan with parallel decoupled lookback: ptr[n] = global exclusive
// prefix of cnt. lb[bid] = (flag<<32)|value; flag 1 = aggregate, 2 = inclusive
// prefix. All blocks co-resident (nc ~ 98 << CU count); wave 3 does a 64-wide
// parallel lookback. Agent-scope atomics for cross-XCD safety.
// ---------------------------------------------------------------------------
__global__ __launch_bounds__(256) void k_scan(
    const int* __restrict__ cnt, int* __restrict__ ptr,
    unsigned long long* __restrict__ lb, int N)
{
    __shared__ int s[256];
    __shared__ int sbase;
    const int t   = threadIdx.x;
    const int bid = blockIdx.x;
    const int lane = t & 63;
    const int w    = t >> 6;

    int base = bid * 1024 + t * 4;
    int v0 = 0, v1 = 0, v2 = 0, v3 = 0;
    if (base + 3 < N) {
        int4 q = *(const int4*)&cnt[base];
        v0 = q.x; v1 = q.y; v2 = q.z; v3 = q.w;
    } else {
        if (base + 0 < N) v0 = cnt[base + 0];
        if (base + 1 < N) v1 = cnt[base + 1];
        if (base + 2 < N) v2 = cnt[base + 2];
        if (base + 3 < N) v3 = cnt[base + 3];
    }
    int sum = v0 + v1 + v2 + v3;
    s[t] = sum;
    __syncthreads();
    for (int off = 1; off < 256; off <<= 1) {
        int xv = (t >= off) ? s[t - off] : 0;
        __syncthreads();
        s[t] += xv;
        __syncthreads();
    }
    int excl  = s[t] - sum;
    int total = s[255];

    // publish own aggregate (block 0 publishes its inclusive prefix directly)
    if (t == 255) {
        unsigned long long pkt =
            ((unsigned long long)((bid == 0) ? 2u : 1u) << 32) | (unsigned)total;
        __hip_atomic_store(&lb[bid], pkt, __ATOMIC_RELEASE, __HIP_MEMORY_SCOPE_AGENT);
        if (bid == 0) sbase = 0;
    }

    // wave 3: parallel lookback
    if (bid > 0 && w == 3) {
        int exclb = 0;
        int j = bid - 1;
        while (true) {
            int idx = j - lane;
            unsigned f = 0; int v = 0;
            if (idx >= 0) {
                unsigned long long p;
                do {
                    p = __hip_atomic_load(&lb[idx], __ATOMIC_ACQUIRE, __HIP_MEMORY_SCOPE_AGENT);
                    f = (unsigned)(p >> 32);
                } while (f == 0);
                v = (int)(unsigned)(p & 0xffffffffu);
            }
            unsigned long long m2 = __ballot(f == 2u);
            if (m2) {
                int Lstop = __ffsll((long long)m2) - 1;   // nearest flag-2 predecessor
                int contrib = (lane <= Lstop) ? v : 0;
                exclb += red64i(contrib);
                break;
            } else {
                exclb += red64i((idx >= 0) ? v : 0);
                j -= 64;
            }
        }
        if (lane == 0) {
            unsigned long long pkt2 =
                ((unsigned long long)2u << 32) | (unsigned)(exclb + total);
            __hip_atomic_store(&lb[bid], pkt2, __ATOMIC_RELEASE, __HIP_MEMORY_SCOPE_AGENT);
            sbase = exclb;
        }
    }
    __syncthreads();

    int r = excl + sbase;
    if (base + 0 < N) ptr[base + 0] = r; r += v0;
    if (base + 1 < N) ptr[base + 1] = r; r += v1;
    if (base + 2 < N) ptr[base + 2] = r; r += v2;
    if (base + 3 < N) ptr[base + 3] = r;
}

// scatter, rank-based (no atomics): pos = global excl start + per-edge rank.
// ptr stays pristine (exclusive).
__global__ __launch_bounds__(256) void k_scatter_rank(
    const int* __restrict__ ei, const float* __restrict__ ew,
    const int* __restrict__ ptr, const int* __restrict__ rank,
    int2* __restrict__ sorted, int E)
{
    int e = blockIdx.x * 256 + threadIdx.x;
    if (e >= E) return;
    int src = ei[e];
    int dst = ei[E + e];
    float w = ew[e];
    int pos = ptr[dst] + rank[e];
    sorted[pos] = make_int2(src << 8, __float_as_int(w));
}

// fallback scatter with atomics (destroys ptr -> ptr becomes inclusive end)
__global__ __launch_bounds__(256) void k_scatter_atomic(
    const int* __restrict__ ei, const float* __restrict__ ew,
    int* __restrict__ ptr, int2* __restrict__ sorted, int E)
{
    int e = blockIdx.x * 256 + threadIdx.x;
    if (e >= E) return;
    int src = ei[e];
    int dst = ei[E + e];
    float w = ew[e];
    int pos = atomicAdd(&ptr[dst], 1);
    sorted[pos] = make_int2(src << 8, __float_as_int(w));
}

// ---------------------------------------------------------------------------
// Fused aggregation + epilogue: 16 lanes per node (4 nodes per wave64).
// Lane owns dims 8*li .. 8*li+7 (uint4 = 16 B per gathered row).
// 4-edge unrolled gather for memory-level parallelism.
// rmode=1: ptr is exclusive start (rank path). rmode=0: ptr is inclusive end.
// ---------------------------------------------------------------------------
__global__ __launch_bounds__(256) void k_agg_final(
    const char* __restrict__ htb, const int* __restrict__ ptr,
    const int* __restrict__ cnt, const int2* __restrict__ sorted,
    const float* __restrict__ a_in, float* __restrict__ out, int N, int rmode)
{
    const int t   = threadIdx.x;
    const int li  = t & 15;          // lane within 16-lane group
    const int grp = t >> 4;          // group within block (0..15)
    const int n   = blockIdx.x * 16 + grp;
    if (n >= N) return;
    const float a = a_in[0];

    H8 own; own.u4 = *(const uint4*)(htb + (size_t)n * 256 + li * 16);
    float acc[8];
#pragma unroll
    for (int k = 0; k < 8; ++k) acc[k] = (float)own.h[k];

    int basep = ptr[n];
    int cn    = cnt[n];
    int s0    = rmode ? basep : basep - cn;
    int e0    = s0 + cn;

    const int lioff = li * 16;
    int j = s0;
    for (; j + 4 <= e0; j += 4) {
        int2 d0 = sorted[j];
        int2 d1 = sorted[j + 1];
        int2 d2 = sorted[j + 2];
        int2 d3 = sorted[j + 3];
        H8 g0, g1, g2, g3;
        g0.u4 = *(const uint4*)(htb + (unsigned)d0.x + lioff);
        g1.u4 = *(const uint4*)(htb + (unsigned)d1.x + lioff);
        g2.u4 = *(const uint4*)(htb + (unsigned)d2.x + lioff);
        g3.u4 = *(const uint4*)(htb + (unsigned)d3.x + lioff);
        float w0 = __int_as_float(d0.y);
        float w1 = __int_as_float(d1.y);
        float w2 = __int_as_float(d2.y);
        float w3 = __int_as_float(d3.y);
#pragma unroll
        for (int k = 0; k < 8; ++k) acc[k] = fmaf((float)g0.h[k], w0, acc[k]);
#pragma unroll
        for (int k = 0; k < 8; ++k) acc[k] = fmaf((float)g1.h[k], w1, acc[k]);
#pragma unroll
        for (int k = 0; k < 8; ++k) acc[k] = fmaf((float)g2.h[k], w2, acc[k]);
#pragma unroll
        for (int k = 0; k < 8; ++k) acc[k] = fmaf((float)g3.h[k], w3, acc[k]);
    }
    for (; j < e0; ++j) {
        int2 d = sorted[j];
        H8 g; g.u4 = *(const uint4*)(htb + (unsigned)d.x + lioff);
        float w = __int_as_float(d.y);
#pragma unroll
        for (int k = 0; k < 8; ++k) acc[k] = fmaf((float)g.h[k], w, acc[k]);
    }

    // h2_t = acc; PReLU
    float pv = 0.f;
#pragma unroll
    for (int k = 0; k < 8; ++k) {
        float v = acc[k];
        v = (v >= 0.f) ? v : a * v;
        acc[k] = v;
        pv = fmaf(v, v, pv);
    }
    float m2 = red16(pv);
    float rc = fmaxf(sqrtf(m2), MINN);
    float te = tanh_fast(rc);
    const float maxn = 1.0f - BALLEPS;
    float fsc = __fdividef(fminf(fmaxf(te, MINN), maxn), rc);

    float4 o0 = make_float4(fsc * acc[0], fsc * acc[1], fsc * acc[2], fsc * acc[3]);
    float4 o1 = make_float4(fsc * acc[4], fsc * acc[5], fsc * acc[6], fsc * acc[7]);
    float4* orow = (float4*)(out + (size_t)n * D);
    orow[li * 2 + 0] = o0;
    orow[li * 2 + 1] = o1;
}

// ---------------------------------------------------------------------------
extern "C" void kernel_launch(void* const* d_in, const int* in_sizes, int n_in,
                              void* d_out, int out_size, void* d_ws, size_t ws_size,
                              hipStream_t stream)
{
    const float* x  = (const float*)d_in[0];
    const int*   ei = (const int*)  d_in[1];
    const float* ew = (const float*)d_in[2];
    const float* W  = (const float*)d_in[3];
    const float* b  = (const float*)d_in[4];
    const float* a  = (const float*)d_in[5];
    float* out = (float*)d_out;

    const int N = in_sizes[0] / D;
    const int E = in_sizes[1] / 2;
    const int nc = (N + 1023) / 1024;

    // workspace carve-up
    char* ws = (char*)d_ws;
    size_t HT_B       = (size_t)N * D * 2;          // fp16 h_t
    uint2*              ht  = (uint2*)ws;
    size_t off_cnt    = HT_B;
    int*                cnt = (int*)(ws + off_cnt);
    size_t off_lb     = (off_cnt + (size_t)N * 4 + 15) & ~(size_t)15;
    unsigned long long* lb  = (unsigned long long*)(ws + off_lb);
    size_t off_ptr    = (off_lb + (size_t)nc * 8 + 15) & ~(size_t)15;
    int*                ptr = (int*)(ws + off_ptr);
    size_t off_sorted = (off_ptr + (size_t)N * 4 + 15) & ~(size_t)15;
    int2*               sorted = (int2*)(ws + off_sorted);
    size_t off_wh     = off_sorted + (size_t)E * 8;
    _Float16*           Wh  = (_Float16*)(ws + off_wh);
    size_t off_rank   = off_wh + 32768;
    int*                rank = (int*)(ws + off_rank);
    int use_rank = (ws_size >= off_rank + (size_t)E * 4) ? 1 : 0;

    int zeroInts = (int)((off_ptr - off_cnt) / 4);   // cnt + lb (+pad)
    int zb  = ((zeroInts + 3) / 4 + 255) / 256;
    int nb1 = (N + 63) / 64;                         // 64 nodes / block (r1 grid)
    int eslice = (E + nb1 - 1) / nb1;

    k_prep<<<8 + zb, 256, 0, stream>>>(W, Wh, cnt, zeroInts);
    k_node_mfma<<<nb1, BLK, 0, stream>>>(x, Wh, b, ht, N, ei, cnt,
                                         use_rank ? rank : nullptr, E, eslice, use_rank);
    k_scan<<<nc, 256, 0, stream>>>(cnt, ptr, lb, N);
    if (use_rank)
        k_scatter_rank<<<(E + 255) / 256, 256, 0, stream>>>(ei, ew, ptr, rank, sorted, E);
    else
        k_scatter_atomic<<<(E + 255) / 256, 256, 0, stream>>>(ei, ew, ptr, sorted, E);
    k_agg_final<<<(N + 15) / 16, 256, 0, stream>>>((const char*)ht, ptr, cnt, sorted, a, out, N, use_rank);
}